// Round 1
// baseline (6100.637 us; speedup 1.0000x reference)
//
#include <hip/hip_runtime.h>

typedef unsigned short u16;
typedef unsigned int u32;
using bf16x8 = __attribute__((ext_vector_type(8))) short;
using f32x4  = __attribute__((ext_vector_type(4))) float;

__device__ __forceinline__ u16 f2bf(float f) {
  u32 u = __float_as_uint(f);
  u32 r = (u + 0x7fffu + ((u >> 16) & 1u)) >> 16;
  return (u16)r;
}

__device__ __forceinline__ void gl2lds16(const void* g, void* l) {
  __builtin_amdgcn_global_load_lds((const __attribute__((address_space(1))) u32*)g,
                                   (__attribute__((address_space(3))) u32*)l, 16, 0, 0);
}

// ---------------- embedding gather + bf16 cast: x[t*64+b][:] = emb[inputs[b][t]][:]
__global__ __launch_bounds__(256) void embed_kernel(const int* __restrict__ inp,
                                                    const float* __restrict__ emb,
                                                    u16* __restrict__ x) {
  int m = blockIdx.x;            // = t*64 + b
  int t = m >> 6, b = m & 63;
  int idx = inp[b * 128 + t];
  const float4* src = (const float4*)(emb + (long)idx * 1024);
  float4 v = src[threadIdx.x];
  u32 lo = (u32)f2bf(v.x) | ((u32)f2bf(v.y) << 16);
  u32 hi = (u32)f2bf(v.z) | ((u32)f2bf(v.w) << 16);
  uint2 o; o.x = lo; o.y = hi;
  *(uint2*)(x + (long)m * 1024 + threadIdx.x * 4) = o;
}

// ---------------- cast + transpose: in fp32 [1024][N] -> out bf16 [N][1024]
__global__ __launch_bounds__(256) void castT_kernel(const float* __restrict__ in,
                                                    u16* __restrict__ outp, int N) {
  __shared__ float tile[32][33];
  int n0 = blockIdx.x * 32, k0 = blockIdx.y * 32;
  int tx = threadIdx.x & 31, ty = threadIdx.x >> 5;  // ty 0..7
  #pragma unroll
  for (int i = 0; i < 4; i++)
    tile[ty + 8 * i][tx] = in[(long)(k0 + ty + 8 * i) * N + n0 + tx];
  __syncthreads();
  #pragma unroll
  for (int i = 0; i < 4; i++)
    outp[(long)(n0 + ty + 8 * i) * 1024 + k0 + tx] = f2bf(tile[tx][ty + 8 * i]);
}

// ---------------- m97-style bt-GEMM: C[M][N] = A[M][1024] * Bm[N][1024]^T + bias
// XOR-swizzled LDS chunks (chunk slot ^= row&7) -> <=2-way bank aliasing on ds_read_b128.
__global__ __launch_bounds__(256) void gemm_bt(const u16* __restrict__ A,
                                               const u16* __restrict__ Bm,
                                               const float* __restrict__ bias,
                                               float* __restrict__ C,
                                               int N, int remap) {
  __shared__ u16 As[128 * 64];
  __shared__ u16 Bs[128 * 64];
  const int K = 1024;
  int bn = blockIdx.x, bm = blockIdx.y;
  int tid = threadIdx.x;
  int lane = tid & 63, w = tid >> 6;
  int wy = w >> 1, wx = w & 1;
  int q = lane >> 4, ml = lane & 15;
  int l8 = lane >> 3, s = lane & 7;
  f32x4 acc[4][4] = {};

  const u16* Abase = A + (long)bm * 128 * K;
  const u16* Bbase = Bm + (long)bn * 128 * K;

  for (int kb = 0; kb < 16; kb++) {
    #pragma unroll
    for (int i = 0; i < 4; i++) {
      int row = w * 32 + i * 8 + l8;
      int kc = s ^ (row & 7);
      gl2lds16(Abase + (long)row * K + kb * 64 + kc * 8, &As[(w * 256 + i * 64) * 8]);
    }
    #pragma unroll
    for (int i = 0; i < 4; i++) {
      int row = w * 32 + i * 8 + l8;
      int kc = s ^ (row & 7);
      gl2lds16(Bbase + (long)row * K + kb * 64 + kc * 8, &Bs[(w * 256 + i * 64) * 8]);
    }
    __syncthreads();
    #pragma unroll
    for (int kk = 0; kk < 2; kk++) {
      bf16x8 av[4], bv[4];
      #pragma unroll
      for (int m = 0; m < 4; m++) {
        int r = wy * 64 + m * 16 + ml;
        int p = kk * 4 + q;
        av[m] = *(const bf16x8*)&As[r * 64 + ((p ^ (r & 7)) << 3)];
      }
      #pragma unroll
      for (int n = 0; n < 4; n++) {
        int r = wx * 64 + n * 16 + ml;
        int p = kk * 4 + q;
        bv[n] = *(const bf16x8*)&Bs[r * 64 + ((p ^ (r & 7)) << 3)];
      }
      #pragma unroll
      for (int m = 0; m < 4; m++)
        #pragma unroll
        for (int n = 0; n < 4; n++)
          acc[m][n] = __builtin_amdgcn_mfma_f32_16x16x32_bf16(av[m], bv[n], acc[m][n], 0, 0, 0);
    }
    __syncthreads();
  }
  #pragma unroll
  for (int n = 0; n < 4; n++) {
    int col = bn * 128 + wx * 64 + n * 16 + ml;
    float bvv = bias[col];
    #pragma unroll
    for (int m = 0; m < 4; m++) {
      #pragma unroll
      for (int r = 0; r < 4; r++) {
        int row = bm * 128 + wy * 64 + m * 16 + q * 4 + r;     // row = t*64+b
        int orow = remap ? (((row & 63) << 7) | (row >> 6)) : row;  // -> b*128+t
        C[(long)orow * N + col] = acc[m][n][r] + bvv;
      }
    }
  }
}

// ---------------- persistent cooperative LSTM scan (one layer)
// 128 WGs; WG k owns h-cols [8k,8k+8) -> 32 U-cols resident in 64KB LDS (swizzled).
__global__ __launch_bounds__(256) void lstm_scan(const float* __restrict__ xz,
                                                 const u16* __restrict__ UT,
                                                 u16* __restrict__ out_seq,
                                                 u16* __restrict__ h_buf, // [2][64][1024] bf16
                                                 float* __restrict__ hT,
                                                 float* __restrict__ cT,
                                                 u32* __restrict__ bar) {
  __shared__ u16 U_lds[32 * 1024];     // 64 KB, chunk-swizzled
  int wg = blockIdx.x;                 // 0..127
  int c0 = wg * 8;
  int tid = threadIdx.x;
  int lane = tid & 63, w = tid >> 6;
  int q = lane >> 4, ml = lane & 15, j = lane & 7;
  bool act = (lane & 8) == 0;

  // stage U slice: LDS row n (gate g=n>>3, col j=n&7) <- UT[g*1024 + c0 + j][:]
  for (int cidx = tid; cidx < 4096; cidx += 256) {
    int n = cidx >> 7;
    int kc = cidx & 127;
    int g = n >> 3, jj = n & 7;
    const u16* src = UT + (long)(g * 1024 + c0 + jj) * 1024 + kc * 8;
    uint4 v = *(const uint4*)src;
    *(uint4*)&U_lds[n * 1024 + ((kc ^ (n & 7)) << 3)] = v;
  }
  // zero own slice of h_buf[0]
  for (int i = tid; i < 512; i += 256)
    h_buf[(i >> 3) * 1024 + c0 + (i & 7)] = 0;

  float cst[4] = {0.f, 0.f, 0.f, 0.f};
  __syncthreads();
  if (tid == 0) {  // initial grid barrier (slot 128)
    __threadfence();
    __hip_atomic_fetch_add(&bar[128], 1u, __ATOMIC_RELAXED, __HIP_MEMORY_SCOPE_AGENT);
    while (__hip_atomic_load(&bar[128], __ATOMIC_RELAXED, __HIP_MEMORY_SCOPE_AGENT) < 128u) {}
    __threadfence();
  }
  __syncthreads();

  for (int t = 0; t < 128; t++) {
    const u16* hcur = h_buf + (t & 1) * 65536;
    u16* hnxt = h_buf + ((t + 1) & 1) * 65536;
    float zi[4], zf[4], zg[4], zo[4];
    if (act) {  // prefetch xz (no dependency on h) before the MFMA loop
      #pragma unroll
      for (int r = 0; r < 4; r++) {
        long base = ((long)(t * 64 + w * 16 + q * 4 + r)) * 4096 + c0 + j;
        zi[r] = xz[base];
        zf[r] = xz[base + 1024];
        zg[r] = xz[base + 2048];
        zo[r] = xz[base + 3072];
      }
    }
    f32x4 acc0 = {}, acc1 = {};
    #pragma unroll 8
    for (int ki = 0; ki < 32; ki++) {
      bf16x8 a = *(const bf16x8*)&hcur[(w * 16 + ml) * 1024 + ki * 32 + q * 8];
      int sw = ((ki * 4 + q) ^ j) << 3;
      bf16x8 b0 = *(const bf16x8*)&U_lds[ml * 1024 + sw];
      bf16x8 b1 = *(const bf16x8*)&U_lds[(16 + ml) * 1024 + sw];
      acc0 = __builtin_amdgcn_mfma_f32_16x16x32_bf16(a, b0, acc0, 0, 0, 0);
      acc1 = __builtin_amdgcn_mfma_f32_16x16x32_bf16(a, b1, acc1, 0, 0, 0);
    }
    // lane l (l&8==0): acc0=i, acc1=g ; partner l^8: acc0=f, acc1=o
    float pf[4], po[4];
    #pragma unroll
    for (int r = 0; r < 4; r++) {
      pf[r] = __shfl_xor(acc0[r], 8, 64);
      po[r] = __shfl_xor(acc1[r], 8, 64);
    }
    if (act) {
      #pragma unroll
      for (int r = 0; r < 4; r++) {
        int b = w * 16 + q * 4 + r;
        float iv = 1.f / (1.f + __expf(-(zi[r] + acc0[r])));
        float fv = 1.f / (1.f + __expf(-(zf[r] + pf[r])));
        float gv = tanhf(zg[r] + acc1[r]);
        float ov = 1.f / (1.f + __expf(-(zo[r] + po[r])));
        cst[r] = fv * cst[r] + iv * gv;
        float hv = ov * tanhf(cst[r]);
        u16 hb = f2bf(hv);
        hnxt[b * 1024 + c0 + j] = hb;
        out_seq[((long)(t * 64 + b)) * 1024 + c0 + j] = hb;
        if (t == 127) {
          hT[b * 1024 + c0 + j] = hv;
          cT[b * 1024 + c0 + j] = cst[r];
        }
      }
    }
    __syncthreads();               // each wave drains its own vmcnt here
    if (tid == 0) {                // per-step grid barrier, slot t (no reuse -> no ABA)
      __threadfence();             // L2 writeback (cross-XCD visibility)
      __hip_atomic_fetch_add(&bar[t], 1u, __ATOMIC_RELAXED, __HIP_MEMORY_SCOPE_AGENT);
      while (__hip_atomic_load(&bar[t], __ATOMIC_RELAXED, __HIP_MEMORY_SCOPE_AGENT) < 128u) {}
      __threadfence();             // invalidate stale L1/L2 before next-step reads
    }
    __syncthreads();
  }
}

extern "C" void kernel_launch(void* const* d_in, const int* in_sizes, int n_in,
                              void* d_out, int out_size, void* d_ws, size_t ws_size,
                              hipStream_t stream) {
  const int*   inputs = (const int*)d_in[0];
  const float* emb    = (const float*)d_in[1];
  const float* W1     = (const float*)d_in[2];
  const float* U1     = (const float*)d_in[3];
  const float* b1     = (const float*)d_in[4];
  const float* W2     = (const float*)d_in[5];
  const float* U2     = (const float*)d_in[6];
  const float* b2     = (const float*)d_in[7];
  const float* Wout   = (const float*)d_in[8];
  const float* bout   = (const float*)d_in[9];
  float* out = (float*)d_out;
  char* ws = (char*)d_ws;

  size_t off = 0;
  float* xz  = (float*)(ws + off); off += (size_t)8192 * 4096 * 4;   // 134 MB, reused by both layers
  u16* xbf   = (u16*)(ws + off);   off += (size_t)8192 * 1024 * 2;   // x, later reused as out2
  u16* out1  = (u16*)(ws + off);   off += (size_t)8192 * 1024 * 2;
  u16* WT    = (u16*)(ws + off);   off += (size_t)4096 * 1024 * 2;
  u16* UT    = (u16*)(ws + off);   off += (size_t)4096 * 1024 * 2;
  u16* WoT   = (u16*)(ws + off);   off += (size_t)32000 * 1024 * 2;
  u16* hbuf  = (u16*)(ws + off);   off += (size_t)2 * 64 * 1024 * 2;
  u32* bar   = (u32*)(ws + off);   off += 4096;                      // total ~239 MiB

  float* hT1 = out + (size_t)262144000;
  float* cT1 = hT1 + 65536;
  float* hT2 = cT1 + 65536;
  float* cT2 = hT2 + 65536;

  hipMemsetAsync(bar, 0, 4096, stream);
  embed_kernel<<<8192, 256, 0, stream>>>(inputs, emb, xbf);

  // ---- layer 1
  castT_kernel<<<dim3(128, 32), 256, 0, stream>>>(W1, WT, 4096);
  gemm_bt<<<dim3(32, 64), 256, 0, stream>>>(xbf, WT, b1, xz, 4096, 0);
  castT_kernel<<<dim3(128, 32), 256, 0, stream>>>(U1, UT, 4096);
  {
    const float* p_xz = xz; const u16* p_ut = UT; u16* p_os = out1; u16* p_hb = hbuf;
    float* p_hT = hT1; float* p_cT = cT1; u32* p_bar = bar;
    void* args[] = {&p_xz, &p_ut, &p_os, &p_hb, &p_hT, &p_cT, &p_bar};
    hipLaunchCooperativeKernel((void*)lstm_scan, dim3(128), dim3(256), args, 0, stream);
  }

  // ---- layer 2
  castT_kernel<<<dim3(128, 32), 256, 0, stream>>>(W2, WT, 4096);
  gemm_bt<<<dim3(32, 64), 256, 0, stream>>>(out1, WT, b2, xz, 4096, 0);
  castT_kernel<<<dim3(128, 32), 256, 0, stream>>>(U2, UT, 4096);
  {
    const float* p_xz = xz; const u16* p_ut = UT; u16* p_os = xbf; u16* p_hb = hbuf;
    float* p_hT = hT2; float* p_cT = cT2; u32* p_bar = bar + 256;
    void* args[] = {&p_xz, &p_ut, &p_os, &p_hb, &p_hT, &p_cT, &p_bar};
    hipLaunchCooperativeKernel((void*)lstm_scan, dim3(128), dim3(256), args, 0, stream);
  }

  // ---- logits
  castT_kernel<<<dim3(1000, 32), 256, 0, stream>>>(Wout, WoT, 32000);
  gemm_bt<<<dim3(250, 64), 256, 0, stream>>>(xbf, WoT, bout, out, 32000, 1);
}